// Round 1
// baseline (65696.838 us; speedup 1.0000x reference)
//
#include <hip/hip_runtime.h>
#include <hip/hip_bf16.h>
#include <math.h>

constexpr int TSEQ = 8192;
constexpr int BH   = 768;
constexpr int HID  = 500;
constexpr int H4   = 2000;
constexpr int NTAG = 9;
constexpr int START_TAG = 7;
constexpr int STOP_TAG  = 8;
constexpr float NEGV = -10000.0f;

constexpr int NWG = 63;   // workgroups per direction (8 units each, last has 4)
constexpr int UPW = 8;    // units per workgroup

// workspace layout (in floats)
constexpr size_t XP_OFF = 0;                          // xproj [2][TSEQ][H4]
constexpr size_t XP_SZ  = (size_t)2 * TSEQ * H4;      // 32,768,000
constexpr size_t HS_OFF = XP_OFF + XP_SZ;             // hseq [2][TSEQ][HID]
constexpr size_t HS_SZ  = (size_t)2 * TSEQ * HID;     // 8,192,000
constexpr size_t FT_OFF = HS_OFF + HS_SZ;             // feats [TSEQ][NTAG]
constexpr size_t FT_SZ  = (size_t)TSEQ * NTAG;        // 73,728
constexpr size_t GH_OFF = FT_OFF + FT_SZ;             // h ping-pong [2 dirs][2][512]
constexpr size_t GH_SZ  = (size_t)2 * 2 * 512;        // 2,048
constexpr size_t FLG_OFF = GH_OFF + GH_SZ;            // flags [2 dirs][64] ints

// ---------------------------------------------------------------------------
// Kernel 1: xproj = emb @ w_ih^T + b_ih + b_hh  for both directions
// 128x128 tile, BK=8, 256 threads, 8x8 microtile, fp32 vector FMA.
// grid = (64, 32): y<16 -> forward dir tiles, y>=16 -> backward.
// ---------------------------------------------------------------------------
__global__ __launch_bounds__(256) void xproj_gemm(
    const float* __restrict__ A,
    const float* __restrict__ Wf, const float* __restrict__ Wb,
    const float* __restrict__ bif, const float* __restrict__ bhf,
    const float* __restrict__ bib, const float* __restrict__ bhb,
    float* __restrict__ out)
{
    __shared__ __align__(16) float As[8 * 128];
    __shared__ __align__(16) float Bs[8 * 128];

    const int bx = blockIdx.x, by = blockIdx.y;
    const int d    = by >> 4;
    const int col0 = (by & 15) << 7;
    const int row0 = bx << 7;
    const float* W  = d ? Wb : Wf;
    const float* bi = d ? bib : bif;
    const float* bh = d ? bhb : bhf;

    const int tid = threadIdx.x;
    const int tx = tid & 15, ty = tid >> 4;

    float acc[8][8];
#pragma unroll
    for (int i = 0; i < 8; ++i)
#pragma unroll
        for (int j = 0; j < 8; ++j) acc[i][j] = 0.f;

    const int lm = tid >> 1;          // 0..127
    const int lk = (tid & 1) << 2;    // 0 or 4
    const float* Ap = A + (size_t)(row0 + lm) * BH + lk;
    const int wcol = col0 + lm;
    const bool wok = wcol < H4;
    const float* Wp = W + (size_t)(wok ? wcol : 0) * BH + lk;

    for (int k0 = 0; k0 < BH; k0 += 8) {
        const float4 av = *(const float4*)(Ap + k0);
        float4 bv = make_float4(0.f, 0.f, 0.f, 0.f);
        if (wok) bv = *(const float4*)(Wp + k0);
        __syncthreads();
        As[(lk + 0) * 128 + lm] = av.x;
        As[(lk + 1) * 128 + lm] = av.y;
        As[(lk + 2) * 128 + lm] = av.z;
        As[(lk + 3) * 128 + lm] = av.w;
        Bs[(lk + 0) * 128 + lm] = bv.x;
        Bs[(lk + 1) * 128 + lm] = bv.y;
        Bs[(lk + 2) * 128 + lm] = bv.z;
        Bs[(lk + 3) * 128 + lm] = bv.w;
        __syncthreads();
#pragma unroll
        for (int kk = 0; kk < 8; ++kk) {
            float a[8], b[8];
            *(float4*)&a[0] = *(const float4*)&As[kk * 128 + ty * 8];
            *(float4*)&a[4] = *(const float4*)&As[kk * 128 + ty * 8 + 4];
            *(float4*)&b[0] = *(const float4*)&Bs[kk * 128 + tx * 8];
            *(float4*)&b[4] = *(const float4*)&Bs[kk * 128 + tx * 8 + 4];
#pragma unroll
            for (int i = 0; i < 8; ++i)
#pragma unroll
                for (int j = 0; j < 8; ++j)
                    acc[i][j] = fmaf(a[i], b[j], acc[i][j]);
        }
    }

#pragma unroll
    for (int i = 0; i < 8; ++i) {
        const int r = row0 + ty * 8 + i;
#pragma unroll
        for (int j = 0; j < 8; ++j) {
            const int cc = col0 + tx * 8 + j;
            if (cc < H4)
                out[((size_t)d * TSEQ + r) * H4 + cc] = acc[i][j] + bi[cc] + bh[cc];
        }
    }
}

// ---------------------------------------------------------------------------
// Kernel 2: persistent bidirectional LSTM recurrence.
// grid = 2*NWG blocks (dir = bx&1, wg = bx>>1), 256 threads.
// Each WG owns 8 hidden units: 32 rows of w_hh (4 gates x 8 units) in LDS.
// Per step: spin on flags (device-scope), load full h (500) from LLC,
// 32x512 LDS matvec (wave r8-rows + 64-lane butterfly), gate update on 8
// threads, publish h slice + release flag.
// ---------------------------------------------------------------------------
__global__ __launch_bounds__(256) void lstm_rec(
    const float* __restrict__ whhf, const float* __restrict__ whhb,
    const float* __restrict__ h0, const float* __restrict__ c0,
    const float* __restrict__ xproj_all, float* __restrict__ hseq_all,
    float* ghbase, int* flagbase)
{
    __shared__ __align__(16) float wlds[32 * 512];
    __shared__ float gparts[32];
    __shared__ float cst[UPW];

    const int bx = blockIdx.x;
    const int d = bx & 1, w = bx >> 1;
    const float* whh = d ? whhb : whhf;
    const float* xproj = xproj_all + (size_t)d * TSEQ * H4;
    float* hseq = hseq_all + (size_t)d * TSEQ * HID;
    float* ghb = ghbase + d * 1024;
    int* flg = flagbase + d * 64;

    const int j0 = w * UPW;
    int nu = HID - j0; if (nu > UPW) nu = UPW; if (nu < 0) nu = 0;
    const int tid = threadIdx.x, lane = tid & 63, wv = tid >> 6;

    // stage weights (zero-padded cols 500..511, zero rows for absent units)
    for (int idx = tid; idx < 32 * 512; idx += 256) {
        const int r = idx >> 9, c = idx & 511;
        const int g = r >> 3, u = r & 7;
        float vv = 0.f;
        if (c < HID && u < nu)
            vv = whh[(size_t)(g * HID + j0 + u) * HID + c];
        wlds[idx] = vv;
    }
    if (tid < UPW) cst[tid] = (tid < nu) ? c0[d * HID + j0 + tid] : 0.f;
    if (tid < nu)
        __hip_atomic_store(&ghb[j0 + tid], h0[d * HID + j0 + tid],
                           __ATOMIC_RELAXED, __HIP_MEMORY_SCOPE_AGENT);
    if (w == 0 && tid < 12) {  // zero pads of both ping-pong buffers
        __hip_atomic_store(&ghb[HID + tid], 0.f, __ATOMIC_RELAXED, __HIP_MEMORY_SCOPE_AGENT);
        __hip_atomic_store(&ghb[512 + HID + tid], 0.f, __ATOMIC_RELAXED, __HIP_MEMORY_SCOPE_AGENT);
    }
    __syncthreads();   // drains vmem -> stores at coherence point
    if (tid == 0)
        __hip_atomic_store(&flg[w], 0, __ATOMIC_RELEASE, __HIP_MEMORY_SCOPE_AGENT);

    for (int step = 0; step < TSEQ; ++step) {
        const int t = d ? (TSEQ - 1 - step) : step;

        // prefetch this step's xproj slice (independent of h)
        float xpv0 = 0.f, xpv1 = 0.f, xpv2 = 0.f, xpv3 = 0.f;
        if (tid < nu) {
            const float* xr = xproj + (size_t)t * H4 + j0 + tid;
            xpv0 = xr[0]; xpv1 = xr[HID]; xpv2 = xr[2 * HID]; xpv3 = xr[3 * HID];
        }

        if (wv == 0) {
            for (;;) {
                int fl = step;
                if (lane < NWG)
                    fl = __hip_atomic_load(&flg[lane], __ATOMIC_ACQUIRE, __HIP_MEMORY_SCOPE_AGENT);
                if (__all(fl >= step)) break;
            }
        }
        __syncthreads();

        const float* hsrc = ghb + (step & 1) * 512;
        const float ha0 = __hip_atomic_load(&hsrc[4 * lane + 0], __ATOMIC_RELAXED, __HIP_MEMORY_SCOPE_AGENT);
        const float ha1 = __hip_atomic_load(&hsrc[4 * lane + 1], __ATOMIC_RELAXED, __HIP_MEMORY_SCOPE_AGENT);
        const float ha2 = __hip_atomic_load(&hsrc[4 * lane + 2], __ATOMIC_RELAXED, __HIP_MEMORY_SCOPE_AGENT);
        const float ha3 = __hip_atomic_load(&hsrc[4 * lane + 3], __ATOMIC_RELAXED, __HIP_MEMORY_SCOPE_AGENT);
        const float hb0 = __hip_atomic_load(&hsrc[256 + 4 * lane + 0], __ATOMIC_RELAXED, __HIP_MEMORY_SCOPE_AGENT);
        const float hb1 = __hip_atomic_load(&hsrc[256 + 4 * lane + 1], __ATOMIC_RELAXED, __HIP_MEMORY_SCOPE_AGENT);
        const float hb2 = __hip_atomic_load(&hsrc[256 + 4 * lane + 2], __ATOMIC_RELAXED, __HIP_MEMORY_SCOPE_AGENT);
        const float hb3 = __hip_atomic_load(&hsrc[256 + 4 * lane + 3], __ATOMIC_RELAXED, __HIP_MEMORY_SCOPE_AGENT);

#pragma unroll
        for (int r8 = 0; r8 < 8; ++r8) {
            const int row = wv * 8 + r8;
            const float4 w0 = *(const float4*)&wlds[row * 512 + 4 * lane];
            const float4 w1 = *(const float4*)&wlds[row * 512 + 256 + 4 * lane];
            float p = w0.x * ha0 + w0.y * ha1 + w0.z * ha2 + w0.w * ha3
                    + w1.x * hb0 + w1.y * hb1 + w1.z * hb2 + w1.w * hb3;
            p += __shfl_xor(p, 1, 64);
            p += __shfl_xor(p, 2, 64);
            p += __shfl_xor(p, 4, 64);
            p += __shfl_xor(p, 8, 64);
            p += __shfl_xor(p, 16, 64);
            p += __shfl_xor(p, 32, 64);
            if (lane == 0) gparts[row] = p;
        }
        __syncthreads();

        if (tid < nu) {
            const float gi = gparts[tid]      + xpv0;
            const float gf = gparts[8 + tid]  + xpv1;
            const float gg = gparts[16 + tid] + xpv2;
            const float go = gparts[24 + tid] + xpv3;
            const float si = 1.f / (1.f + expf(-gi));
            const float sf = 1.f / (1.f + expf(-gf));
            const float so = 1.f / (1.f + expf(-go));
            const float c = sf * cst[tid] + si * tanhf(gg);
            cst[tid] = c;
            const float h = so * tanhf(c);
            hseq[(size_t)t * HID + j0 + tid] = h;
            __hip_atomic_store(&ghb[((step + 1) & 1) * 512 + j0 + tid], h,
                               __ATOMIC_RELAXED, __HIP_MEMORY_SCOPE_AGENT);
        }
        __syncthreads();   // drains the h stores
        if (tid == 0)
            __hip_atomic_store(&flg[w], step + 1, __ATOMIC_RELEASE, __HIP_MEMORY_SCOPE_AGENT);
    }
}

// ---------------------------------------------------------------------------
// Kernel 3: feats[t][n] = b_tag[n] + sum_k w_tag[n][k] * lstm_out[t][k]
// One wave per t, w_tag staged in LDS.
// ---------------------------------------------------------------------------
__global__ __launch_bounds__(256) void feats_kern(
    const float* __restrict__ hsf, const float* __restrict__ hsb,
    const float* __restrict__ wtag, const float* __restrict__ btag,
    float* __restrict__ feats)
{
    __shared__ float wt[NTAG * 1000];
    __shared__ float bt[NTAG];
    const int tid = threadIdx.x;
    for (int idx = tid; idx < NTAG * 1000; idx += 256) wt[idx] = wtag[idx];
    if (tid < NTAG) bt[tid] = btag[tid];
    __syncthreads();

    const int t = blockIdx.x * 4 + (tid >> 6);
    const int l = tid & 63;
    float acc[NTAG];
#pragma unroll
    for (int n = 0; n < NTAG; ++n) acc[n] = 0.f;

#pragma unroll
    for (int j = 0; j < 16; ++j) {
        const int k = l + 64 * j;
        if (k < 1000) {
            const float a = (k < HID) ? hsf[(size_t)t * HID + k]
                                      : hsb[(size_t)t * HID + k - HID];
#pragma unroll
            for (int n = 0; n < NTAG; ++n)
                acc[n] = fmaf(wt[n * 1000 + k], a, acc[n]);
        }
    }
#pragma unroll
    for (int n = 0; n < NTAG; ++n) {
        acc[n] += __shfl_xor(acc[n], 1, 64);
        acc[n] += __shfl_xor(acc[n], 2, 64);
        acc[n] += __shfl_xor(acc[n], 4, 64);
        acc[n] += __shfl_xor(acc[n], 8, 64);
        acc[n] += __shfl_xor(acc[n], 16, 64);
        acc[n] += __shfl_xor(acc[n], 32, 64);
    }
    if (l < NTAG) feats[(size_t)t * NTAG + l] = acc[l] + bt[l];
}

// ---------------------------------------------------------------------------
// Kernel 4: Viterbi. Wave0 forward pass (fv per lane, readlane broadcast,
// first-max argmax semantics), bptrs in LDS; parallel 2-phase backtrack.
// ---------------------------------------------------------------------------
__global__ __launch_bounds__(256) void viterbi_kern(
    const float* __restrict__ feats, const float* __restrict__ trans,
    float* __restrict__ out)
{
    __shared__ unsigned char bp[TSEQ * NTAG];        // 73,728 B
    __shared__ float fch[512 * NTAG];                // 18,432 B
    __shared__ unsigned char amap[256];
    __shared__ unsigned char entry[32];
    __shared__ int s_best;

    const int tid = threadIdx.x, l = tid & 63, wv = tid >> 6;
    const int ln = (l < NTAG) ? l : 0;
    float tr[NTAG];
#pragma unroll
    for (int p = 0; p < NTAG; ++p) tr[p] = trans[ln * NTAG + p];
    float fv = (l == START_TAG) ? 0.f : NEGV;

    for (int c = 0; c < 16; ++c) {
        for (int idx = tid; idx < 512 * NTAG; idx += 256)
            fch[idx] = feats[(size_t)c * 512 * NTAG + idx];
        __syncthreads();
        if (wv == 0) {
            for (int tt = 0; tt < 512; ++tt) {
                const float ft = fch[tt * NTAG + ln];
                float best = __shfl(fv, 0, 64) + tr[0];
                int b = 0;
#pragma unroll
                for (int p = 1; p < NTAG; ++p) {
                    const float s = __shfl(fv, p, 64) + tr[p];
                    if (s > best) { best = s; b = p; }
                }
                fv = best + ft;
                if (l < NTAG) bp[(size_t)(c * 512 + tt) * NTAG + l] = (unsigned char)b;
            }
        }
        __syncthreads();
    }

    if (wv == 0) {
        const float term = (l < NTAG) ? (fv + trans[STOP_TAG * NTAG + l]) : -3.0e38f;
        float bestv = __shfl(term, 0, 64);
        int bi = 0;
#pragma unroll
        for (int p = 1; p < NTAG; ++p) {
            const float s = __shfl(term, p, 64);
            if (s > bestv) { bestv = s; bi = p; }
        }
        if (l == 0) { out[0] = bestv; s_best = bi; }
    }
    __syncthreads();

    // phase A: per-chunk tag maps (28 chunks x 9 tags, 252 threads)
    if (tid < 252) {
        const int ch = tid / 9, tg = tid % 9;
        const int s = ch * 293;
        const int e = (s + 293 < TSEQ) ? s + 293 : TSEQ;
        int tag = tg;
        for (int t = e - 1; t >= s; --t) tag = bp[t * NTAG + tag];
        amap[ch * 9 + tg] = (unsigned char)tag;
    }
    __syncthreads();
    if (tid == 0) {
        int tag = s_best;
        entry[27] = (unsigned char)tag;
        for (int ch = 27; ch >= 1; --ch) {
            tag = amap[ch * 9 + tag];
            entry[ch - 1] = (unsigned char)tag;
        }
    }
    __syncthreads();
    // phase B: 28 parallel emit walks
    if (tid < 28) {
        const int ch = tid;
        const int s = ch * 293;
        const int e = (s + 293 < TSEQ) ? s + 293 : TSEQ;
        int tag = entry[ch];
        for (int t = e - 1; t >= s; --t) {
            out[1 + t] = (float)tag;
            tag = bp[t * NTAG + tag];
        }
    }
}

// ---------------------------------------------------------------------------
extern "C" void kernel_launch(void* const* d_in, const int* in_sizes, int n_in,
                              void* d_out, int out_size, void* d_ws, size_t ws_size,
                              hipStream_t stream) {
    const float* emb  = (const float*)d_in[0];
    const float* wihf = (const float*)d_in[1];
    const float* whhf = (const float*)d_in[2];
    const float* bihf = (const float*)d_in[3];
    const float* bhhf = (const float*)d_in[4];
    const float* wihb = (const float*)d_in[5];
    const float* whhb = (const float*)d_in[6];
    const float* bihb = (const float*)d_in[7];
    const float* bhhb = (const float*)d_in[8];
    const float* h0   = (const float*)d_in[9];
    const float* c0   = (const float*)d_in[10];
    const float* wtag = (const float*)d_in[11];
    const float* btag = (const float*)d_in[12];
    const float* trans = (const float*)d_in[13];

    float* ws = (float*)d_ws;
    float* out = (float*)d_out;

    xproj_gemm<<<dim3(64, 32), 256, 0, stream>>>(
        emb, wihf, wihb, bihf, bhhf, bihb, bhhb, ws + XP_OFF);

    lstm_rec<<<2 * NWG, 256, 0, stream>>>(
        whhf, whhb, h0, c0, ws + XP_OFF, ws + HS_OFF,
        ws + GH_OFF, (int*)(ws + FLG_OFF));

    feats_kern<<<TSEQ / 4, 256, 0, stream>>>(
        ws + HS_OFF, ws + HS_OFF + (size_t)TSEQ * HID, wtag, btag, ws + FT_OFF);

    viterbi_kern<<<1, 256, 0, stream>>>(ws + FT_OFF, trans, out);
}

// Round 2
// 30898.163 us; speedup vs baseline: 2.1262x; 2.1262x over previous
//
#include <hip/hip_runtime.h>
#include <hip/hip_bf16.h>
#include <math.h>

constexpr int TSEQ = 8192;
constexpr int BH   = 768;
constexpr int HID  = 500;
constexpr int H4   = 2000;
constexpr int NTAG = 9;
constexpr int START_TAG = 7;
constexpr int STOP_TAG  = 8;
constexpr float NEGV = -10000.0f;

constexpr int NWG = 32;   // workgroups per direction (16 units each, last has 4)
constexpr int UPW = 16;   // units per workgroup

// workspace layout (in floats; BUF region is 8-byte aligned by construction)
constexpr size_t XP_OFF = 0;                          // xproj [2][TSEQ][H4]
constexpr size_t XP_SZ  = (size_t)2 * TSEQ * H4;      // 32,768,000
constexpr size_t HS_OFF = XP_OFF + XP_SZ;             // hseq [2][TSEQ][HID]
constexpr size_t HS_SZ  = (size_t)2 * TSEQ * HID;     // 8,192,000
constexpr size_t FT_OFF = HS_OFF + HS_SZ;             // feats [TSEQ][NTAG]
constexpr size_t FT_SZ  = (size_t)TSEQ * NTAG;        // 73,728
constexpr size_t BUF_OFF = FT_OFF + FT_SZ;            // h bufs [2 dirs][2][512] ull
// BUF_OFF = 41,033,728 floats (even -> 8B aligned). BUF = 2*2*512 ull = 16 KB.

// ---------------------------------------------------------------------------
// Kernel 1: xproj = emb @ w_ih^T + b_ih + b_hh  for both directions
// (unchanged from round 1 — verified correct)
// ---------------------------------------------------------------------------
__global__ __launch_bounds__(256) void xproj_gemm(
    const float* __restrict__ A,
    const float* __restrict__ Wf, const float* __restrict__ Wb,
    const float* __restrict__ bif, const float* __restrict__ bhf,
    const float* __restrict__ bib, const float* __restrict__ bhb,
    float* __restrict__ out)
{
    __shared__ __align__(16) float As[8 * 128];
    __shared__ __align__(16) float Bs[8 * 128];

    const int bx = blockIdx.x, by = blockIdx.y;
    const int d    = by >> 4;
    const int col0 = (by & 15) << 7;
    const int row0 = bx << 7;
    const float* W  = d ? Wb : Wf;
    const float* bi = d ? bib : bif;
    const float* bh = d ? bhb : bhf;

    const int tid = threadIdx.x;
    const int tx = tid & 15, ty = tid >> 4;

    float acc[8][8];
#pragma unroll
    for (int i = 0; i < 8; ++i)
#pragma unroll
        for (int j = 0; j < 8; ++j) acc[i][j] = 0.f;

    const int lm = tid >> 1;          // 0..127
    const int lk = (tid & 1) << 2;    // 0 or 4
    const float* Ap = A + (size_t)(row0 + lm) * BH + lk;
    const int wcol = col0 + lm;
    const bool wok = wcol < H4;
    const float* Wp = W + (size_t)(wok ? wcol : 0) * BH + lk;

    for (int k0 = 0; k0 < BH; k0 += 8) {
        const float4 av = *(const float4*)(Ap + k0);
        float4 bv = make_float4(0.f, 0.f, 0.f, 0.f);
        if (wok) bv = *(const float4*)(Wp + k0);
        __syncthreads();
        As[(lk + 0) * 128 + lm] = av.x;
        As[(lk + 1) * 128 + lm] = av.y;
        As[(lk + 2) * 128 + lm] = av.z;
        As[(lk + 3) * 128 + lm] = av.w;
        Bs[(lk + 0) * 128 + lm] = bv.x;
        Bs[(lk + 1) * 128 + lm] = bv.y;
        Bs[(lk + 2) * 128 + lm] = bv.z;
        Bs[(lk + 3) * 128 + lm] = bv.w;
        __syncthreads();
#pragma unroll
        for (int kk = 0; kk < 8; ++kk) {
            float a[8], b[8];
            *(float4*)&a[0] = *(const float4*)&As[kk * 128 + ty * 8];
            *(float4*)&a[4] = *(const float4*)&As[kk * 128 + ty * 8 + 4];
            *(float4*)&b[0] = *(const float4*)&Bs[kk * 128 + tx * 8];
            *(float4*)&b[4] = *(const float4*)&Bs[kk * 128 + tx * 8 + 4];
#pragma unroll
            for (int i = 0; i < 8; ++i)
#pragma unroll
                for (int j = 0; j < 8; ++j)
                    acc[i][j] = fmaf(a[i], b[j], acc[i][j]);
        }
    }

#pragma unroll
    for (int i = 0; i < 8; ++i) {
        const int r = row0 + ty * 8 + i;
#pragma unroll
        for (int j = 0; j < 8; ++j) {
            const int cc = col0 + tx * 8 + j;
            if (cc < H4)
                out[((size_t)d * TSEQ + r) * H4 + cc] = acc[i][j] + bi[cc] + bh[cc];
        }
    }
}

// ---------------------------------------------------------------------------
// Kernel 2: persistent bidirectional LSTM recurrence, fused data+tag sync.
// grid = 2*NWG blocks (dir = bx&1, wg = bx>>1), 512 threads.
// Each WG owns 16 hidden units: 64 rows of w_hh (4 gates x 16) in 128 KB LDS.
// h is published as packed {tag=step+1, f32 value} 8-byte atoms into a
// ping-pong global buffer; consumers poll the DATA (tag match == valid):
// one LLC round trip per step, no separate flags, relaxed atomics only.
// Exact-tag match + parity makes overwrite-before-read impossible.
// ---------------------------------------------------------------------------
__global__ __launch_bounds__(512) void lstm_rec(
    const float* __restrict__ whhf, const float* __restrict__ whhb,
    const float* __restrict__ h0, const float* __restrict__ c0,
    const float* __restrict__ xproj_all, float* __restrict__ hseq_all,
    unsigned long long* bufbase)
{
    __shared__ __align__(16) float wlds[64 * 512];   // 128 KB
    __shared__ __align__(16) float hs[512];
    __shared__ float gparts[64];

    const int bx = blockIdx.x;
    const int d = bx & 1, w = bx >> 1;
    const float* whh = d ? whhb : whhf;
    const float* xproj = xproj_all + (size_t)d * TSEQ * H4;
    float* hseq = hseq_all + (size_t)d * TSEQ * HID;
    unsigned long long* bufd = bufbase + d * 1024;   // [2][512] ull per dir

    const int j0 = w * UPW;
    int nu = HID - j0; if (nu > UPW) nu = UPW; if (nu < 0) nu = 0;
    const int tid = threadIdx.x, l = tid & 63, wv = tid >> 6;

    // stage weights (zero cols 500..511 and rows for absent units)
    for (int idx = tid; idx < 64 * 512; idx += 512) {
        const int r = idx >> 9, c = idx & 511;
        const int g = r >> 4, u = r & 15;
        float vv = 0.f;
        if (c < HID && u < nu)
            vv = whh[(size_t)(g * HID + j0 + u) * HID + c];
        wlds[idx] = vv;
    }
    float creg = 0.f;
    if (tid < nu) {
        creg = c0[d * HID + j0 + tid];
        const unsigned long long pk =
            (unsigned long long)__float_as_uint(h0[d * HID + j0 + tid]);  // tag 0
        __hip_atomic_store(&bufd[j0 + tid], pk,
                           __ATOMIC_RELAXED, __HIP_MEMORY_SCOPE_AGENT);
    }
    __syncthreads();

    const int ua = 4 * l, ub = 256 + 4 * l;

    for (int step = 0; step < TSEQ; ++step) {
        const int t = d ? (TSEQ - 1 - step) : step;

        // prefetch this step's xproj slice (independent of h; hides HBM lat)
        float xp0 = 0.f, xp1 = 0.f, xp2 = 0.f, xp3 = 0.f;
        if (tid < nu) {
            const float* xr = xproj + (size_t)t * H4 + j0 + tid;
            xp0 = xr[0]; xp1 = xr[HID]; xp2 = xr[2 * HID]; xp3 = xr[3 * HID];
        }

        if (wv == 0) {
            unsigned long long* bp = bufd + ((step & 1) << 9);
            const unsigned long long want = (unsigned long long)(unsigned)step;
            unsigned long long va0, va1, va2, va3, vb0, vb1, vb2, vb3;
            for (;;) {
                va0 = __hip_atomic_load(&bp[ua + 0], __ATOMIC_RELAXED, __HIP_MEMORY_SCOPE_AGENT);
                va1 = __hip_atomic_load(&bp[ua + 1], __ATOMIC_RELAXED, __HIP_MEMORY_SCOPE_AGENT);
                va2 = __hip_atomic_load(&bp[ua + 2], __ATOMIC_RELAXED, __HIP_MEMORY_SCOPE_AGENT);
                va3 = __hip_atomic_load(&bp[ua + 3], __ATOMIC_RELAXED, __HIP_MEMORY_SCOPE_AGENT);
                vb0 = __hip_atomic_load(&bp[ub + 0], __ATOMIC_RELAXED, __HIP_MEMORY_SCOPE_AGENT);
                vb1 = __hip_atomic_load(&bp[ub + 1], __ATOMIC_RELAXED, __HIP_MEMORY_SCOPE_AGENT);
                vb2 = __hip_atomic_load(&bp[ub + 2], __ATOMIC_RELAXED, __HIP_MEMORY_SCOPE_AGENT);
                vb3 = __hip_atomic_load(&bp[ub + 3], __ATOMIC_RELAXED, __HIP_MEMORY_SCOPE_AGENT);
                bool ok = true;
                ok &= (ua + 0 >= HID) || ((va0 >> 32) == want);
                ok &= (ua + 1 >= HID) || ((va1 >> 32) == want);
                ok &= (ua + 2 >= HID) || ((va2 >> 32) == want);
                ok &= (ua + 3 >= HID) || ((va3 >> 32) == want);
                ok &= (ub + 0 >= HID) || ((vb0 >> 32) == want);
                ok &= (ub + 1 >= HID) || ((vb1 >> 32) == want);
                ok &= (ub + 2 >= HID) || ((vb2 >> 32) == want);
                ok &= (ub + 3 >= HID) || ((vb3 >> 32) == want);
                if (__all(ok)) break;
            }
            float4 fa, fb;
            fa.x = __uint_as_float((unsigned)va0);
            fa.y = __uint_as_float((unsigned)va1);
            fa.z = __uint_as_float((unsigned)va2);
            fa.w = __uint_as_float((unsigned)va3);
            fb.x = __uint_as_float((unsigned)vb0);
            fb.y = __uint_as_float((unsigned)vb1);
            fb.z = __uint_as_float((unsigned)vb2);
            fb.w = __uint_as_float((unsigned)vb3);
            *(float4*)&hs[ua] = fa;
            *(float4*)&hs[ub] = fb;
        }
        __syncthreads();   // B1: hs valid

        const float4 ha = *(const float4*)&hs[ua];
        const float4 hb = *(const float4*)&hs[ub];
#pragma unroll
        for (int r8 = 0; r8 < 8; ++r8) {
            const int row = (wv << 3) + r8;
            const float4 w0 = *(const float4*)&wlds[(row << 9) + ua];
            const float4 w1 = *(const float4*)&wlds[(row << 9) + ub];
            float p = w0.x * ha.x + w0.y * ha.y + w0.z * ha.z + w0.w * ha.w
                    + w1.x * hb.x + w1.y * hb.y + w1.z * hb.z + w1.w * hb.w;
            p += __shfl_xor(p, 1, 64);
            p += __shfl_xor(p, 2, 64);
            p += __shfl_xor(p, 4, 64);
            p += __shfl_xor(p, 8, 64);
            p += __shfl_xor(p, 16, 64);
            p += __shfl_xor(p, 32, 64);
            if (l == 0) gparts[row] = p;
        }
        __syncthreads();   // B2: gparts valid

        if (tid < nu) {
            const float gi = gparts[tid]      + xp0;
            const float gf = gparts[16 + tid] + xp1;
            const float gg = gparts[32 + tid] + xp2;
            const float go = gparts[48 + tid] + xp3;
            const float si = 1.f / (1.f + expf(-gi));
            const float sf = 1.f / (1.f + expf(-gf));
            const float so = 1.f / (1.f + expf(-go));
            const float c = sf * creg + si * tanhf(gg);
            creg = c;
            const float h = so * tanhf(c);
            hseq[(size_t)t * HID + j0 + tid] = h;
            const unsigned long long pk =
                ((unsigned long long)(unsigned)(step + 1) << 32) | __float_as_uint(h);
            __hip_atomic_store(&bufd[(((step + 1) & 1) << 9) + j0 + tid], pk,
                               __ATOMIC_RELAXED, __HIP_MEMORY_SCOPE_AGENT);
        }
        // no trailing barrier needed: wave0 (the producer wave) polls next;
        // waves 1-7 wait at B1.
    }
}

// ---------------------------------------------------------------------------
// Kernel 3: feats[t][n] = b_tag[n] + sum_k w_tag[n][k] * lstm_out[t][k]
// (unchanged from round 1 — verified correct)
// ---------------------------------------------------------------------------
__global__ __launch_bounds__(256) void feats_kern(
    const float* __restrict__ hsf, const float* __restrict__ hsb,
    const float* __restrict__ wtag, const float* __restrict__ btag,
    float* __restrict__ feats)
{
    __shared__ float wt[NTAG * 1000];
    __shared__ float bt[NTAG];
    const int tid = threadIdx.x;
    for (int idx = tid; idx < NTAG * 1000; idx += 256) wt[idx] = wtag[idx];
    if (tid < NTAG) bt[tid] = btag[tid];
    __syncthreads();

    const int t = blockIdx.x * 4 + (tid >> 6);
    const int l = tid & 63;
    float acc[NTAG];
#pragma unroll
    for (int n = 0; n < NTAG; ++n) acc[n] = 0.f;

#pragma unroll
    for (int j = 0; j < 16; ++j) {
        const int k = l + 64 * j;
        if (k < 1000) {
            const float a = (k < HID) ? hsf[(size_t)t * HID + k]
                                      : hsb[(size_t)t * HID + k - HID];
#pragma unroll
            for (int n = 0; n < NTAG; ++n)
                acc[n] = fmaf(wt[n * 1000 + k], a, acc[n]);
        }
    }
#pragma unroll
    for (int n = 0; n < NTAG; ++n) {
        acc[n] += __shfl_xor(acc[n], 1, 64);
        acc[n] += __shfl_xor(acc[n], 2, 64);
        acc[n] += __shfl_xor(acc[n], 4, 64);
        acc[n] += __shfl_xor(acc[n], 8, 64);
        acc[n] += __shfl_xor(acc[n], 16, 64);
        acc[n] += __shfl_xor(acc[n], 32, 64);
    }
    if (l < NTAG) feats[(size_t)t * NTAG + l] = acc[l] + bt[l];
}

// ---------------------------------------------------------------------------
// Kernel 4: Viterbi (unchanged from round 1 — verified correct)
// ---------------------------------------------------------------------------
__global__ __launch_bounds__(256) void viterbi_kern(
    const float* __restrict__ feats, const float* __restrict__ trans,
    float* __restrict__ out)
{
    __shared__ unsigned char bp[TSEQ * NTAG];        // 73,728 B
    __shared__ float fch[512 * NTAG];                // 18,432 B
    __shared__ unsigned char amap[256];
    __shared__ unsigned char entry[32];
    __shared__ int s_best;

    const int tid = threadIdx.x, l = tid & 63, wv = tid >> 6;
    const int ln = (l < NTAG) ? l : 0;
    float tr[NTAG];
#pragma unroll
    for (int p = 0; p < NTAG; ++p) tr[p] = trans[ln * NTAG + p];
    float fv = (l == START_TAG) ? 0.f : NEGV;

    for (int c = 0; c < 16; ++c) {
        for (int idx = tid; idx < 512 * NTAG; idx += 256)
            fch[idx] = feats[(size_t)c * 512 * NTAG + idx];
        __syncthreads();
        if (wv == 0) {
            for (int tt = 0; tt < 512; ++tt) {
                const float ft = fch[tt * NTAG + ln];
                float best = __shfl(fv, 0, 64) + tr[0];
                int b = 0;
#pragma unroll
                for (int p = 1; p < NTAG; ++p) {
                    const float s = __shfl(fv, p, 64) + tr[p];
                    if (s > best) { best = s; b = p; }
                }
                fv = best + ft;
                if (l < NTAG) bp[(size_t)(c * 512 + tt) * NTAG + l] = (unsigned char)b;
            }
        }
        __syncthreads();
    }

    if (wv == 0) {
        const float term = (l < NTAG) ? (fv + trans[STOP_TAG * NTAG + l]) : -3.0e38f;
        float bestv = __shfl(term, 0, 64);
        int bi = 0;
#pragma unroll
        for (int p = 1; p < NTAG; ++p) {
            const float s = __shfl(term, p, 64);
            if (s > bestv) { bestv = s; bi = p; }
        }
        if (l == 0) { out[0] = bestv; s_best = bi; }
    }
    __syncthreads();

    // phase A: per-chunk tag maps (28 chunks x 9 tags, 252 threads)
    if (tid < 252) {
        const int ch = tid / 9, tg = tid % 9;
        const int s = ch * 293;
        const int e = (s + 293 < TSEQ) ? s + 293 : TSEQ;
        int tag = tg;
        for (int t = e - 1; t >= s; --t) tag = bp[t * NTAG + tag];
        amap[ch * 9 + tg] = (unsigned char)tag;
    }
    __syncthreads();
    if (tid == 0) {
        int tag = s_best;
        entry[27] = (unsigned char)tag;
        for (int ch = 27; ch >= 1; --ch) {
            tag = amap[ch * 9 + tag];
            entry[ch - 1] = (unsigned char)tag;
        }
    }
    __syncthreads();
    // phase B: 28 parallel emit walks
    if (tid < 28) {
        const int ch = tid;
        const int s = ch * 293;
        const int e = (s + 293 < TSEQ) ? s + 293 : TSEQ;
        int tag = entry[ch];
        for (int t = e - 1; t >= s; --t) {
            out[1 + t] = (float)tag;
            tag = bp[t * NTAG + tag];
        }
    }
}

// ---------------------------------------------------------------------------
extern "C" void kernel_launch(void* const* d_in, const int* in_sizes, int n_in,
                              void* d_out, int out_size, void* d_ws, size_t ws_size,
                              hipStream_t stream) {
    const float* emb  = (const float*)d_in[0];
    const float* wihf = (const float*)d_in[1];
    const float* whhf = (const float*)d_in[2];
    const float* bihf = (const float*)d_in[3];
    const float* bhhf = (const float*)d_in[4];
    const float* wihb = (const float*)d_in[5];
    const float* whhb = (const float*)d_in[6];
    const float* bihb = (const float*)d_in[7];
    const float* bhhb = (const float*)d_in[8];
    const float* h0   = (const float*)d_in[9];
    const float* c0   = (const float*)d_in[10];
    const float* wtag = (const float*)d_in[11];
    const float* btag = (const float*)d_in[12];
    const float* trans = (const float*)d_in[13];

    float* ws = (float*)d_ws;
    float* out = (float*)d_out;

    xproj_gemm<<<dim3(64, 32), 256, 0, stream>>>(
        emb, wihf, wihb, bihf, bhhf, bihb, bhhb, ws + XP_OFF);

    lstm_rec<<<2 * NWG, 512, 0, stream>>>(
        whhf, whhb, h0, c0, ws + XP_OFF, ws + HS_OFF,
        (unsigned long long*)(ws + BUF_OFF));

    feats_kern<<<TSEQ / 4, 256, 0, stream>>>(
        ws + HS_OFF, ws + HS_OFF + (size_t)TSEQ * HID, wtag, btag, ws + FT_OFF);

    viterbi_kern<<<1, 256, 0, stream>>>(ws + FT_OFF, trans, out);
}

// Round 3
// 20878.336 us; speedup vs baseline: 3.1467x; 1.4799x over previous
//
#include <hip/hip_runtime.h>
#include <hip/hip_bf16.h>
#include <math.h>

constexpr int TSEQ = 8192;
constexpr int BH   = 768;
constexpr int HID  = 500;
constexpr int H4   = 2000;
constexpr int NTAG = 9;
constexpr int START_TAG = 7;
constexpr int STOP_TAG  = 8;
constexpr float NEGV = -10000.0f;

constexpr int NWG = 32;   // workgroups per direction (16 units each, last has 4)
constexpr int UPW = 16;   // units per workgroup

// workspace layout (in floats; BUF region is 8-byte aligned by construction)
constexpr size_t XP_OFF = 0;                          // xproj [2][TSEQ][H4]
constexpr size_t XP_SZ  = (size_t)2 * TSEQ * H4;      // 32,768,000
constexpr size_t HS_OFF = XP_OFF + XP_SZ;             // hseq [2][TSEQ][HID]
constexpr size_t HS_SZ  = (size_t)2 * TSEQ * HID;     // 8,192,000
constexpr size_t FT_OFF = HS_OFF + HS_SZ;             // feats [TSEQ][NTAG]
constexpr size_t FT_SZ  = (size_t)TSEQ * NTAG;        // 73,728
constexpr size_t BUF_OFF = FT_OFF + FT_SZ;            // h bufs [2 dirs][2][512] ull

// 64-lane sum via DPP (VALU pipe, ~12 ops) instead of 6 ds_bpermute (~700cy).
// Hillis-Steele within 16 (row_shr 1/2/4/8), then row_bcast15 + row_bcast31.
// Full sum lands in lane 63.
__device__ __forceinline__ float wave_reduce_sum(float v) {
    int x;
    x = __builtin_amdgcn_update_dpp(0, __float_as_int(v), 0x111, 0xF, 0xF, true);
    v += __int_as_float(x);
    x = __builtin_amdgcn_update_dpp(0, __float_as_int(v), 0x112, 0xF, 0xF, true);
    v += __int_as_float(x);
    x = __builtin_amdgcn_update_dpp(0, __float_as_int(v), 0x114, 0xF, 0xF, true);
    v += __int_as_float(x);
    x = __builtin_amdgcn_update_dpp(0, __float_as_int(v), 0x118, 0xF, 0xF, true);
    v += __int_as_float(x);
    x = __builtin_amdgcn_update_dpp(0, __float_as_int(v), 0x142, 0xF, 0xF, true); // bcast15
    v += __int_as_float(x);
    x = __builtin_amdgcn_update_dpp(0, __float_as_int(v), 0x143, 0xF, 0xF, true); // bcast31
    v += __int_as_float(x);
    return v;
}

// ---------------------------------------------------------------------------
// Kernel 1: xproj = emb @ w_ih^T + b_ih + b_hh  (unchanged — verified)
// ---------------------------------------------------------------------------
__global__ __launch_bounds__(256) void xproj_gemm(
    const float* __restrict__ A,
    const float* __restrict__ Wf, const float* __restrict__ Wb,
    const float* __restrict__ bif, const float* __restrict__ bhf,
    const float* __restrict__ bib, const float* __restrict__ bhb,
    float* __restrict__ out)
{
    __shared__ __align__(16) float As[8 * 128];
    __shared__ __align__(16) float Bs[8 * 128];

    const int bx = blockIdx.x, by = blockIdx.y;
    const int d    = by >> 4;
    const int col0 = (by & 15) << 7;
    const int row0 = bx << 7;
    const float* W  = d ? Wb : Wf;
    const float* bi = d ? bib : bif;
    const float* bh = d ? bhb : bhf;

    const int tid = threadIdx.x;
    const int tx = tid & 15, ty = tid >> 4;

    float acc[8][8];
#pragma unroll
    for (int i = 0; i < 8; ++i)
#pragma unroll
        for (int j = 0; j < 8; ++j) acc[i][j] = 0.f;

    const int lm = tid >> 1;
    const int lk = (tid & 1) << 2;
    const float* Ap = A + (size_t)(row0 + lm) * BH + lk;
    const int wcol = col0 + lm;
    const bool wok = wcol < H4;
    const float* Wp = W + (size_t)(wok ? wcol : 0) * BH + lk;

    for (int k0 = 0; k0 < BH; k0 += 8) {
        const float4 av = *(const float4*)(Ap + k0);
        float4 bv = make_float4(0.f, 0.f, 0.f, 0.f);
        if (wok) bv = *(const float4*)(Wp + k0);
        __syncthreads();
        As[(lk + 0) * 128 + lm] = av.x;
        As[(lk + 1) * 128 + lm] = av.y;
        As[(lk + 2) * 128 + lm] = av.z;
        As[(lk + 3) * 128 + lm] = av.w;
        Bs[(lk + 0) * 128 + lm] = bv.x;
        Bs[(lk + 1) * 128 + lm] = bv.y;
        Bs[(lk + 2) * 128 + lm] = bv.z;
        Bs[(lk + 3) * 128 + lm] = bv.w;
        __syncthreads();
#pragma unroll
        for (int kk = 0; kk < 8; ++kk) {
            float a[8], b[8];
            *(float4*)&a[0] = *(const float4*)&As[kk * 128 + ty * 8];
            *(float4*)&a[4] = *(const float4*)&As[kk * 128 + ty * 8 + 4];
            *(float4*)&b[0] = *(const float4*)&Bs[kk * 128 + tx * 8];
            *(float4*)&b[4] = *(const float4*)&Bs[kk * 128 + tx * 8 + 4];
#pragma unroll
            for (int i = 0; i < 8; ++i)
#pragma unroll
                for (int j = 0; j < 8; ++j)
                    acc[i][j] = fmaf(a[i], b[j], acc[i][j]);
        }
    }

#pragma unroll
    for (int i = 0; i < 8; ++i) {
        const int r = row0 + ty * 8 + i;
#pragma unroll
        for (int j = 0; j < 8; ++j) {
            const int cc = col0 + tx * 8 + j;
            if (cc < H4)
                out[((size_t)d * TSEQ + r) * H4 + cc] = acc[i][j] + bi[cc] + bh[cc];
        }
    }
}

// ---------------------------------------------------------------------------
// Kernel 2: persistent bidirectional LSTM recurrence, fused data+tag sync.
// Same protocol as round 2 (packed {tag,value} atoms, ping-pong, exact tag
// match). Change: shfl_xor LDS-pipe reduction -> DPP VALU reduction.
// ---------------------------------------------------------------------------
__global__ __launch_bounds__(512) void lstm_rec(
    const float* __restrict__ whhf, const float* __restrict__ whhb,
    const float* __restrict__ h0, const float* __restrict__ c0,
    const float* __restrict__ xproj_all, float* __restrict__ hseq_all,
    unsigned long long* bufbase)
{
    __shared__ __align__(16) float wlds[64 * 512];   // 128 KB
    __shared__ __align__(16) float hs[512];
    __shared__ float gparts[64];

    const int bx = blockIdx.x;
    const int d = bx & 1, w = bx >> 1;
    const float* whh = d ? whhb : whhf;
    const float* xproj = xproj_all + (size_t)d * TSEQ * H4;
    float* hseq = hseq_all + (size_t)d * TSEQ * HID;
    unsigned long long* bufd = bufbase + d * 1024;   // [2][512] ull per dir

    const int j0 = w * UPW;
    int nu = HID - j0; if (nu > UPW) nu = UPW; if (nu < 0) nu = 0;
    const int tid = threadIdx.x, l = tid & 63, wv = tid >> 6;

    for (int idx = tid; idx < 64 * 512; idx += 512) {
        const int r = idx >> 9, c = idx & 511;
        const int g = r >> 4, u = r & 15;
        float vv = 0.f;
        if (c < HID && u < nu)
            vv = whh[(size_t)(g * HID + j0 + u) * HID + c];
        wlds[idx] = vv;
    }
    float creg = 0.f;
    if (tid < nu) {
        creg = c0[d * HID + j0 + tid];
        const unsigned long long pk =
            (unsigned long long)__float_as_uint(h0[d * HID + j0 + tid]);  // tag 0
        __hip_atomic_store(&bufd[j0 + tid], pk,
                           __ATOMIC_RELAXED, __HIP_MEMORY_SCOPE_AGENT);
    }
    __syncthreads();

    const int ua = 4 * l, ub = 256 + 4 * l;
    // ua+k < 500 always; only ub+k can exceed HID (never-written pad slots)
    const bool gb0 = (ub + 0 >= HID), gb1 = (ub + 1 >= HID);
    const bool gb2 = (ub + 2 >= HID), gb3 = (ub + 3 >= HID);

    for (int step = 0; step < TSEQ; ++step) {
        const int t = d ? (TSEQ - 1 - step) : step;

        float xp0 = 0.f, xp1 = 0.f, xp2 = 0.f, xp3 = 0.f;
        if (tid < nu) {
            const float* xr = xproj + (size_t)t * H4 + j0 + tid;
            xp0 = xr[0]; xp1 = xr[HID]; xp2 = xr[2 * HID]; xp3 = xr[3 * HID];
        }

        if (wv == 0) {
            unsigned long long* bp = bufd + ((step & 1) << 9);
            const unsigned long long want = (unsigned long long)(unsigned)step;
            unsigned long long va0, va1, va2, va3, vb0, vb1, vb2, vb3;
            for (;;) {
                va0 = __hip_atomic_load(&bp[ua + 0], __ATOMIC_RELAXED, __HIP_MEMORY_SCOPE_AGENT);
                va1 = __hip_atomic_load(&bp[ua + 1], __ATOMIC_RELAXED, __HIP_MEMORY_SCOPE_AGENT);
                va2 = __hip_atomic_load(&bp[ua + 2], __ATOMIC_RELAXED, __HIP_MEMORY_SCOPE_AGENT);
                va3 = __hip_atomic_load(&bp[ua + 3], __ATOMIC_RELAXED, __HIP_MEMORY_SCOPE_AGENT);
                vb0 = __hip_atomic_load(&bp[ub + 0], __ATOMIC_RELAXED, __HIP_MEMORY_SCOPE_AGENT);
                vb1 = __hip_atomic_load(&bp[ub + 1], __ATOMIC_RELAXED, __HIP_MEMORY_SCOPE_AGENT);
                vb2 = __hip_atomic_load(&bp[ub + 2], __ATOMIC_RELAXED, __HIP_MEMORY_SCOPE_AGENT);
                vb3 = __hip_atomic_load(&bp[ub + 3], __ATOMIC_RELAXED, __HIP_MEMORY_SCOPE_AGENT);
                bool ok = true;
                ok &= ((va0 >> 32) == want);
                ok &= ((va1 >> 32) == want);
                ok &= ((va2 >> 32) == want);
                ok &= ((va3 >> 32) == want);
                ok &= gb0 || ((vb0 >> 32) == want);
                ok &= gb1 || ((vb1 >> 32) == want);
                ok &= gb2 || ((vb2 >> 32) == want);
                ok &= gb3 || ((vb3 >> 32) == want);
                if (__all(ok)) break;
            }
            float4 fa, fb;
            fa.x = __uint_as_float((unsigned)va0);
            fa.y = __uint_as_float((unsigned)va1);
            fa.z = __uint_as_float((unsigned)va2);
            fa.w = __uint_as_float((unsigned)va3);
            fb.x = __uint_as_float((unsigned)vb0);
            fb.y = __uint_as_float((unsigned)vb1);
            fb.z = __uint_as_float((unsigned)vb2);
            fb.w = __uint_as_float((unsigned)vb3);
            *(float4*)&hs[ua] = fa;
            *(float4*)&hs[ub] = fb;
        }
        __syncthreads();   // B1: hs valid

        const float4 ha = *(const float4*)&hs[ua];
        const float4 hb = *(const float4*)&hs[ub];
#pragma unroll
        for (int r8 = 0; r8 < 8; ++r8) {
            const int row = (wv << 3) + r8;
            const float4 w0 = *(const float4*)&wlds[(row << 9) + ua];
            const float4 w1 = *(const float4*)&wlds[(row << 9) + ub];
            float p = w0.x * ha.x + w0.y * ha.y + w0.z * ha.z + w0.w * ha.w
                    + w1.x * hb.x + w1.y * hb.y + w1.z * hb.z + w1.w * hb.w;
            p = wave_reduce_sum(p);          // DPP; total in lane 63
            if (l == 63) gparts[row] = p;
        }
        __syncthreads();   // B2: gparts valid

        if (tid < nu) {
            const float gi = gparts[tid]      + xp0;
            const float gf = gparts[16 + tid] + xp1;
            const float gg = gparts[32 + tid] + xp2;
            const float go = gparts[48 + tid] + xp3;
            const float si = 1.f / (1.f + expf(-gi));
            const float sf = 1.f / (1.f + expf(-gf));
            const float so = 1.f / (1.f + expf(-go));
            const float c = sf * creg + si * tanhf(gg);
            creg = c;
            const float h = so * tanhf(c);
            // publish first (critical path), archive second
            const unsigned long long pk =
                ((unsigned long long)(unsigned)(step + 1) << 32) | __float_as_uint(h);
            __hip_atomic_store(&bufd[(((step + 1) & 1) << 9) + j0 + tid], pk,
                               __ATOMIC_RELAXED, __HIP_MEMORY_SCOPE_AGENT);
            hseq[(size_t)t * HID + j0 + tid] = h;
        }
        // waves 1-7 wait at B1; wave0 (producer) proceeds to next poll
    }
}

// ---------------------------------------------------------------------------
// Kernel 3: feats (unchanged — verified)
// ---------------------------------------------------------------------------
__global__ __launch_bounds__(256) void feats_kern(
    const float* __restrict__ hsf, const float* __restrict__ hsb,
    const float* __restrict__ wtag, const float* __restrict__ btag,
    float* __restrict__ feats)
{
    __shared__ float wt[NTAG * 1000];
    __shared__ float bt[NTAG];
    const int tid = threadIdx.x;
    for (int idx = tid; idx < NTAG * 1000; idx += 256) wt[idx] = wtag[idx];
    if (tid < NTAG) bt[tid] = btag[tid];
    __syncthreads();

    const int t = blockIdx.x * 4 + (tid >> 6);
    const int l = tid & 63;
    float acc[NTAG];
#pragma unroll
    for (int n = 0; n < NTAG; ++n) acc[n] = 0.f;

#pragma unroll
    for (int j = 0; j < 16; ++j) {
        const int k = l + 64 * j;
        if (k < 1000) {
            const float a = (k < HID) ? hsf[(size_t)t * HID + k]
                                      : hsb[(size_t)t * HID + k - HID];
#pragma unroll
            for (int n = 0; n < NTAG; ++n)
                acc[n] = fmaf(wt[n * 1000 + k], a, acc[n]);
        }
    }
#pragma unroll
    for (int n = 0; n < NTAG; ++n) {
        acc[n] += __shfl_xor(acc[n], 1, 64);
        acc[n] += __shfl_xor(acc[n], 2, 64);
        acc[n] += __shfl_xor(acc[n], 4, 64);
        acc[n] += __shfl_xor(acc[n], 8, 64);
        acc[n] += __shfl_xor(acc[n], 16, 64);
        acc[n] += __shfl_xor(acc[n], 32, 64);
    }
    if (l < NTAG) feats[(size_t)t * NTAG + l] = acc[l] + bt[l];
}

// ---------------------------------------------------------------------------
// Kernel 4: Viterbi. Forward: fv in LDS, 3 broadcast ds_read_b128 per step
// (instead of 9 serial shfls); max via fmaxf tree (-> v_max3), argmax via
// equality bitmask + ctz (exact first-max semantics). Backtrack unchanged.
// ---------------------------------------------------------------------------
__global__ __launch_bounds__(256) void viterbi_kern(
    const float* __restrict__ feats, const float* __restrict__ trans,
    float* __restrict__ out)
{
    __shared__ unsigned char bp[TSEQ * NTAG];        // 73,728 B
    __shared__ float fch[512 * NTAG];                // 18,432 B
    __shared__ __align__(16) float fvL[12];
    __shared__ unsigned char amap[256];
    __shared__ unsigned char entry[32];
    __shared__ int s_best;

    const int tid = threadIdx.x, l = tid & 63, wv = tid >> 6;
    const int ln = (l < NTAG) ? l : NTAG - 1;
    float tr[NTAG];
#pragma unroll
    for (int p = 0; p < NTAG; ++p) tr[p] = trans[ln * NTAG + p];

    if (tid < 12) fvL[tid] = (tid == START_TAG) ? 0.f : NEGV;
    __syncthreads();

    for (int c = 0; c < 16; ++c) {
        for (int idx = tid; idx < 512 * NTAG; idx += 256)
            fch[idx] = feats[(size_t)c * 512 * NTAG + idx];
        __syncthreads();
        if (wv == 0) {
            for (int tt = 0; tt < 512; ++tt) {
                const float ft = fch[tt * NTAG + ln];
                const float4 f0 = *(const float4*)&fvL[0];
                const float4 f1 = *(const float4*)&fvL[4];
                const float f8 = fvL[8];
                const float c0 = f0.x + tr[0];
                const float c1 = f0.y + tr[1];
                const float c2 = f0.z + tr[2];
                const float c3 = f0.w + tr[3];
                const float c4 = f1.x + tr[4];
                const float c5 = f1.y + tr[5];
                const float c6 = f1.z + tr[6];
                const float c7 = f1.w + tr[7];
                const float c8 = f8   + tr[8];
                const float m0 = fmaxf(fmaxf(c0, c1), c2);
                const float m1 = fmaxf(fmaxf(c3, c4), c5);
                const float m2 = fmaxf(fmaxf(c6, c7), c8);
                const float best = fmaxf(fmaxf(m0, m1), m2);
                unsigned m = (c0 == best ? 1u : 0u)
                           | (c1 == best ? 2u : 0u)
                           | (c2 == best ? 4u : 0u)
                           | (c3 == best ? 8u : 0u)
                           | (c4 == best ? 16u : 0u)
                           | (c5 == best ? 32u : 0u)
                           | (c6 == best ? 64u : 0u)
                           | (c7 == best ? 128u : 0u)
                           | (c8 == best ? 256u : 0u);
                const int b = __builtin_ctz(m);   // first (lowest p) max
                const float nf = best + ft;
                if (l < NTAG) {
                    bp[(size_t)(c * 512 + tt) * NTAG + l] = (unsigned char)b;
                    fvL[l] = nf;
                }
            }
        }
        __syncthreads();
    }

    if (tid == 0) {
        float bestv = -3.0e38f; int bi = 0;
#pragma unroll
        for (int p = 0; p < NTAG; ++p) {
            const float s = fvL[p] + trans[STOP_TAG * NTAG + p];
            if (s > bestv) { bestv = s; bi = p; }
        }
        out[0] = bestv; s_best = bi;
    }
    __syncthreads();

    // phase A: per-chunk tag maps (28 chunks x 9 tags)
    if (tid < 252) {
        const int ch = tid / 9, tg = tid % 9;
        const int s = ch * 293;
        const int e = (s + 293 < TSEQ) ? s + 293 : TSEQ;
        int tag = tg;
        for (int t = e - 1; t >= s; --t) tag = bp[t * NTAG + tag];
        amap[ch * 9 + tg] = (unsigned char)tag;
    }
    __syncthreads();
    if (tid == 0) {
        int tag = s_best;
        entry[27] = (unsigned char)tag;
        for (int ch = 27; ch >= 1; --ch) {
            tag = amap[ch * 9 + tag];
            entry[ch - 1] = (unsigned char)tag;
        }
    }
    __syncthreads();
    // phase B: 28 parallel emit walks
    if (tid < 28) {
        const int ch = tid;
        const int s = ch * 293;
        const int e = (s + 293 < TSEQ) ? s + 293 : TSEQ;
        int tag = entry[ch];
        for (int t = e - 1; t >= s; --t) {
            out[1 + t] = (float)tag;
            tag = bp[t * NTAG + tag];
        }
    }
}

// ---------------------------------------------------------------------------
extern "C" void kernel_launch(void* const* d_in, const int* in_sizes, int n_in,
                              void* d_out, int out_size, void* d_ws, size_t ws_size,
                              hipStream_t stream) {
    const float* emb  = (const float*)d_in[0];
    const float* wihf = (const float*)d_in[1];
    const float* whhf = (const float*)d_in[2];
    const float* bihf = (const float*)d_in[3];
    const float* bhhf = (const float*)d_in[4];
    const float* wihb = (const float*)d_in[5];
    const float* whhb = (const float*)d_in[6];
    const float* bihb = (const float*)d_in[7];
    const float* bhhb = (const float*)d_in[8];
    const float* h0   = (const float*)d_in[9];
    const float* c0   = (const float*)d_in[10];
    const float* wtag = (const float*)d_in[11];
    const float* btag = (const float*)d_in[12];
    const float* trans = (const float*)d_in[13];

    float* ws = (float*)d_ws;
    float* out = (float*)d_out;

    xproj_gemm<<<dim3(64, 32), 256, 0, stream>>>(
        emb, wihf, wihb, bihf, bhhf, bihb, bhhb, ws + XP_OFF);

    lstm_rec<<<2 * NWG, 512, 0, stream>>>(
        whhf, whhb, h0, c0, ws + XP_OFF, ws + HS_OFF,
        (unsigned long long*)(ws + BUF_OFF));

    feats_kern<<<TSEQ / 4, 256, 0, stream>>>(
        ws + HS_OFF, ws + HS_OFF + (size_t)TSEQ * HID, wtag, btag, ws + FT_OFF);

    viterbi_kern<<<1, 256, 0, stream>>>(ws + FT_OFF, trans, out);
}